// Round 10
// baseline (407.272 us; speedup 1.0000x reference)
//
#include <hip/hip_runtime.h>
#include <math.h>

// Problem constants (B=4, T_p=T_f=8, S=256, d=512, heads=8)
#define BB   4
#define SS   256
#define DD   512
#define HH   8
#define HD   64
#define HALF 32
#define TT   32      // total tokens per sequence
#define TV   16      // vp+vf tokens (vary per (b,s))
#define W3   1536    // 3*d
#define MROWS  16448 // 16384 v-rows + 64 unique a-rows
#define MPAD   16512 // 129 * 128

#define VP_BASE 0
#define VF_BASE 4194304      // 4*8*256*512
#define AP_BASE 8388608      // 2*4194304
#define AF_BASE 8404992      // AP_BASE + 4*8*512

#define LN10000_OVER_HALF (9.210340371976184f / 32.0f)

typedef _Float16 h2 __attribute__((ext_vector_type(2)));
typedef _Float16 h4 __attribute__((ext_vector_type(4)));
typedef _Float16 h8 __attribute__((ext_vector_type(8)));
typedef float    f4 __attribute__((ext_vector_type(4)));
typedef float    f16v __attribute__((ext_vector_type(16)));

__device__ __forceinline__ float ropefreq(int i) {
    return __expf(-(float)i * LN10000_OVER_HALF);   // 10000^(-i/32)
}

// async global->LDS, 16 bytes per lane (global_load_lds_dwordx4)
typedef __attribute__((address_space(3))) void*       lds_ptr_t;
typedef const __attribute__((address_space(1))) void* gbl_ptr_t;
__device__ __forceinline__ void async16(const void* g, void* l) {
    __builtin_amdgcn_global_load_lds((gbl_ptr_t)g, (lds_ptr_t)l, 16, 0, 0);
}

// Bijective XCD-aware blockIdx swizzle (m204 formula; works for nwg%8 != 0).
// Maps round-robin XCD assignment into contiguous bid chunks per XCD, so
// blocks sharing an A-panel land on the SAME per-XCD L2.
__device__ __forceinline__ int xcd_swz(int bid, int nwg) {
    int q = nwg >> 3, r = nwg & 7;
    int xcd = bid & 7, off = bid >> 3;
    return (xcd < r ? xcd * (q + 1) : r * (q + 1) + (xcd - r) * q) + off;
}

// ---------------------------------------------------------------------------
// Fused prep kernel.
// Blocks [0, 8224): gather tokens into fp16 tok[16512][512]
//   rows 0..16383: v-tokens (bs=r/16, t=r%16); rows 16384..16447: a-tokens.
// Blocks [8224, 8480): 64x64 LDS-tile transpose+convert Wqkv->Wt, Wp->Wpt.
// Block 8480: RoPE cos/sin table -> rope[1024].
// Block 8481: zero aaccum[128][512] f32 (a-row atomic accumulator; rows
//   64..127 stay zero = pad rows for proj's tm==128 tile).
// ---------------------------------------------------------------------------
__global__ __launch_bounds__(256)
void conv_kernel(const float* __restrict__ v_p, const float* __restrict__ v_f,
                 const float* __restrict__ a_p, const float* __restrict__ a_f,
                 const float* __restrict__ Wqkv, const float* __restrict__ Wp,
                 _Float16* __restrict__ tok, _Float16* __restrict__ Wt,
                 _Float16* __restrict__ Wpt, float2* __restrict__ rope,
                 float* __restrict__ aaccum) {
    __shared__ float tile[64 * 65];
    const int bid = blockIdx.x, tid = threadIdx.x;
    if (bid < 8224) {
        int id = bid * 256 + tid;
        int e  = id * 4;
        int r  = e >> 9, c = e & 511;
        const float* src;
        if (r < 16384) {
            int bs = r >> 4, t = r & 15, b = bs >> 8, s = bs & 255;
            src = (t < 8) ? v_p + (size_t)((b * 8 + t) * SS + s) * DD
                          : v_f + (size_t)((b * 8 + t - 8) * SS + s) * DD;
        } else {
            int idx = r - 16384, b = idx >> 4, t2 = idx & 15;
            src = (t2 < 8) ? a_p + (size_t)(b * 8 + t2) * DD
                           : a_f + (size_t)(b * 8 + (t2 - 8)) * DD;
        }
        float4 v = *(const float4*)(src + c);
        h4 o = { (_Float16)v.x, (_Float16)v.y, (_Float16)v.z, (_Float16)v.w };
        *(h4*)(tok + (size_t)r * DD + c) = o;
    } else if (bid < 8480) {
        int tb = bid - 8224;                 // 0..255
        const float* src; _Float16* dst; int ld, k0, n0;
        if (tb < 192) {                      // Wqkv: 512(k) x 1536(n), 8x24 tiles
            src = Wqkv; dst = Wt; ld = W3;
            k0 = (tb & 7) * 64; n0 = (tb >> 3) * 64;
        } else {                             // Wp: 512 x 512, 8x8 tiles
            int t2 = tb - 192;
            src = Wp; dst = Wpt; ld = DD;
            k0 = (t2 & 7) * 64; n0 = (t2 >> 3) * 64;
        }
#pragma unroll
        for (int p = 0; p < 16; ++p) {
            int idx = p * 256 + tid, rr = idx >> 6, cc = idx & 63;
            tile[rr * 65 + cc] = src[(size_t)(k0 + rr) * ld + n0 + cc];
        }
        __syncthreads();
#pragma unroll
        for (int p = 0; p < 16; ++p) {
            int idx = p * 256 + tid, rr = idx >> 6, cc = idx & 63;
            dst[(size_t)(n0 + rr) * DD + k0 + cc] = (_Float16)tile[cc * 65 + rr];
        }
    } else if (bid == 8480) {
        // RoPE table: rope[t*32 + i] = (cos(t*f_i), sin(t*f_i)), f_i = 10000^(-i/32)
        int idx = tid * 4;
#pragma unroll
        for (int e2 = 0; e2 < 4; ++e2) {
            int ii = (idx + e2) & 31, tt = (idx + e2) >> 5;
            float ang = (float)tt * ropefreq(ii);
            float sn, cs;
            __sincosf(ang, &sn, &cs);
            rope[idx + e2] = make_float2(cs, sn);
        }
    } else {
        // zero aaccum: 128*512 f32 = 65536 floats; 256 threads x 64 float4
        f4 z = {};
#pragma unroll
        for (int p = 0; p < 64; ++p)
            *(f4*)&aaccum[(p * 256 + tid) * 4] = z;
    }
}

// ---------------------------------------------------------------------------
// MFMA GEMM 1 (R3 anchor form): qkv[16512][1536] = tok[16512][512] @ Wqkv.
// 128x128 tiles, BK=64, XOR-swizzled LDS. 1-D grid 129*12, tn-fastest;
// XCD-bijective swizzle for A-panel L2 locality. 3 blk/CU.
// ---------------------------------------------------------------------------
__global__ __launch_bounds__(256, 3)
void gemm_qkv_kernel(const _Float16* __restrict__ A, const _Float16* __restrict__ Bt,
                     _Float16* __restrict__ C) {
    __shared__ __align__(16) _Float16 As[128 * 64];   // 16 KB
    __shared__ __align__(16) _Float16 Bs[128 * 64];   // 16 KB
    const int tid = threadIdx.x, lane = tid & 63, wave = tid >> 6;
    const int bid = xcd_swz(blockIdx.x, 129 * 12);
    const int tm = bid / 12, tn = bid % 12;
    const int m_base = (wave >> 1) * 64, n_base = (wave & 1) * 64;
    const int quad = lane >> 4, l16 = lane & 15;

    f4 acc[4][4] = {};

    int srow[4], soff[4];
#pragma unroll
    for (int p = 0; p < 4; ++p) {
        int ci = p * 256 + tid;            // [0,1024): r = ci>>3, sl = ci&7
        int r = ci >> 3, sl = ci & 7;
        srow[p] = r;
        soff[p] = (sl ^ (r & 7)) * 8;      // swizzled source k-offset
    }

    for (int k0 = 0; k0 < 512; k0 += 64) {
#pragma unroll
        for (int p = 0; p < 4; ++p) {
            int ci = p * 256 + tid;
            async16(A  + (size_t)(tm * 128 + srow[p]) * 512 + k0 + soff[p],
                    &As[ci * 8]);
            async16(Bt + (size_t)(tn * 128 + srow[p]) * 512 + k0 + soff[p],
                    &Bs[ci * 8]);
        }
        __syncthreads();

#pragma unroll
        for (int kk = 0; kk < 2; ++kk) {
            h8 af[4], bf[4];
#pragma unroll
            for (int mi = 0; mi < 4; ++mi) {
                int m = m_base + mi * 16 + l16;
                int sl = (kk * 4 + quad) ^ (m & 7);
                af[mi] = *(const h8*)&As[m * 64 + sl * 8];
            }
#pragma unroll
            for (int ni = 0; ni < 4; ++ni) {
                int n = n_base + ni * 16 + l16;
                int sl = (kk * 4 + quad) ^ (n & 7);
                bf[ni] = *(const h8*)&Bs[n * 64 + sl * 8];
            }
#pragma unroll
            for (int mi = 0; mi < 4; ++mi)
#pragma unroll
                for (int ni = 0; ni < 4; ++ni)
                    acc[mi][ni] = __builtin_amdgcn_mfma_f32_16x16x32_f16(
                        af[mi], bf[ni], acc[mi][ni], 0, 0, 0);
        }
        __syncthreads();
    }

#pragma unroll
    for (int mi = 0; mi < 4; ++mi)
#pragma unroll
        for (int ni = 0; ni < 4; ++ni) {
            int row = tm * 128 + m_base + mi * 16 + quad * 4;
            int col = tn * 128 + n_base + ni * 16 + l16;
#pragma unroll
            for (int r = 0; r < 4; ++r)
                C[(size_t)(row + r) * W3 + col] = (_Float16)acc[mi][ni][r];
        }
}

// ---------------------------------------------------------------------------
// MFMA attention: grid 2048 = (b,s) x head-group; 4 waves, wave w = head
// w + 4*hh. Wave-private LDS; no __syncthreads. RoPE from precomputed table.
// Softmax via DEFERRED NORMALIZATION (R8, verified): E = exp(S) unnormalized
// (scores bounded ~N(0,1), E <= ~450, fp16-safe); rowsum via ones-B MFMA;
// O = (E V) * rcp(rowsum) at the end.
// Outputs: v-rows -> attnv[bs*16+t][c]; a-rows -> f32 atomicAdd into
// aaccum[b*16+t][c] (device-scope) — replaces the attna round-trip and the
// reduce_a dispatch. Same fp16-quantized summands as before; f32 sum order
// differs by atomic scheduling (~f32 ULPs, << 2^-7 fp16 floor).
// ---------------------------------------------------------------------------
__global__ __launch_bounds__(256)
void attn5_kernel(const _Float16* __restrict__ qkv, const float2* __restrict__ rope,
                  _Float16* __restrict__ attnv, float* __restrict__ aaccum) {
    __shared__ _Float16 VlA[4][32 * 72];   // per-wave V tile (reused for O)
    __shared__ _Float16 PlA[4][32 * 40];   // per-wave E tile
    const int bid = blockIdx.x;
    const int bs = bid >> 1, hh = bid & 1, b = bs >> 8, s = bs & 255;
    const int tid = threadIdx.x, wave = tid >> 6, lane = tid & 63;
    const int t = lane & 31, half = lane >> 5;
    _Float16* vl = &VlA[wave][0];
    _Float16* pl = &PlA[wave][0];
    const int h = wave + 4 * hh;

    const size_t row = (t < 16) ? (size_t)(bs * 16 + t)
                                : (size_t)(16384 + b * 16 + (t - 16));
    const _Float16* qp = qkv + row * W3 + h * HD;

    // ---- RoPE coefficients from table (L1/L2-resident, 8 KB) ----
    float ccA[8], ssA[8], ccB[8], ssB[8];
    const float2* rt = rope + t * 32 + 8 * half;
#pragma unroll
    for (int j = 0; j < 8; ++j) {
        float2 eA = rt[j];        // i = 8*half + j
        float2 eB = rt[16 + j];   // i = 16 + 8*half + j
        ccA[j] = eA.x; ssA[j] = eA.y;
        ccB[j] = eB.x; ssB[j] = eB.y;
    }

    // ---- stage V ----
    h8 v0 = *(const h8*)(qp + 2 * DD + 32 * half);
    h8 v1 = *(const h8*)(qp + 2 * DD + 32 * half + 8);
    h8 v2 = *(const h8*)(qp + 2 * DD + 32 * half + 16);
    h8 v3 = *(const h8*)(qp + 2 * DD + 32 * half + 24);
    *(h8*)&vl[t * 72 + 32 * half +  0] = v0;
    *(h8*)&vl[t * 72 + 32 * half +  8] = v1;
    *(h8*)&vl[t * 72 + 32 * half + 16] = v2;
    *(h8*)&vl[t * 72 + 32 * half + 24] = v3;

    // ---- load Q,K chunks + in-register RoPE ----
    h8 q0 = *(const h8*)(qp + 8 * half);
    h8 q1 = *(const h8*)(qp + 8 * half + 16);
    h8 q2 = *(const h8*)(qp + 8 * half + 32);
    h8 q3 = *(const h8*)(qp + 8 * half + 48);
    h8 k0 = *(const h8*)(qp + DD + 8 * half);
    h8 k1 = *(const h8*)(qp + DD + 8 * half + 16);
    h8 k2 = *(const h8*)(qp + DD + 8 * half + 32);
    h8 k3 = *(const h8*)(qp + DD + 8 * half + 48);

    h8 qf0, qf1, qf2, qf3, kf0, kf1, kf2, kf3;
#pragma unroll
    for (int j = 0; j < 8; ++j) {
        float x1 = (float)q0[j], x2 = (float)q2[j];
        qf0[j] = (_Float16)(0.125f * (x1 * ccA[j] - x2 * ssA[j]));
        qf2[j] = (_Float16)(0.125f * (x2 * ccA[j] + x1 * ssA[j]));
        x1 = (float)q1[j]; x2 = (float)q3[j];
        qf1[j] = (_Float16)(0.125f * (x1 * ccB[j] - x2 * ssB[j]));
        qf3[j] = (_Float16)(0.125f * (x2 * ccB[j] + x1 * ssB[j]));
        x1 = (float)k0[j]; x2 = (float)k2[j];
        kf0[j] = (_Float16)(x1 * ccA[j] - x2 * ssA[j]);
        kf2[j] = (_Float16)(x2 * ccA[j] + x1 * ssA[j]);
        x1 = (float)k1[j]; x2 = (float)k3[j];
        kf1[j] = (_Float16)(x1 * ccB[j] - x2 * ssB[j]);
        kf3[j] = (_Float16)(x2 * ccB[j] + x1 * ssB[j]);
    }

    // ---- scores ----
    f16v s4 = {};
    s4 = __builtin_amdgcn_mfma_f32_32x32x16_f16(qf0, kf0, s4, 0, 0, 0);
    s4 = __builtin_amdgcn_mfma_f32_32x32x16_f16(qf1, kf1, s4, 0, 0, 0);
    s4 = __builtin_amdgcn_mfma_f32_32x32x16_f16(qf2, kf2, s4, 0, 0, 0);
    s4 = __builtin_amdgcn_mfma_f32_32x32x16_f16(qf3, kf3, s4, 0, 0, 0);

    // ---- E = exp(S), unnormalized (no max-sub, no shuffle reduction) ----
#pragma unroll
    for (int r = 0; r < 16; ++r) {
        float e = __expf(s4[r]);
        int rr = (r & 3) + 8 * (r >> 2) + 4 * half;
        pl[rr * 40 + t] = (_Float16)e;
    }

    // ---- O' = E V ; rowsum = E * ones (same A-fragments, extra MFMA) ----
    h8 onesv;
#pragma unroll
    for (int j = 0; j < 8; ++j) onesv[j] = (_Float16)1.0f;

    h8 pf[2];
#pragma unroll
    for (int kk = 0; kk < 2; ++kk)
        pf[kk] = *(const h8*)&pl[t * 40 + kk * 16 + half * 8];

    f16v o1 = {};
#pragma unroll
    for (int kk = 0; kk < 2; ++kk)
        o1 = __builtin_amdgcn_mfma_f32_32x32x16_f16(pf[kk], onesv, o1, 0, 0, 0);

    f16v o_acc[2];
#pragma unroll
    for (int n0 = 0; n0 < 2; ++n0) {
        f16v o = {};
#pragma unroll
        for (int kk = 0; kk < 2; ++kk) {
            h8 vf;
#pragma unroll
            for (int jj = 0; jj < 8; ++jj)
                vf[jj] = vl[(kk * 16 + half * 8 + jj) * 72 + n0 * 32 + t];
            o = __builtin_amdgcn_mfma_f32_32x32x16_f16(pf[kk], vf, o, 0, 0, 0);
        }
        o_acc[n0] = o;
    }

    // ---- deferred normalization: O = O' / rowsum ----
#pragma unroll
    for (int r = 0; r < 16; ++r) {
        float inv = __builtin_amdgcn_rcpf(o1[r]);
        o_acc[0][r] *= inv;
        o_acc[1][r] *= inv;
    }

    // ---- V tile dead; stage O into it (wave-synchronous) ----
#pragma unroll
    for (int n0 = 0; n0 < 2; ++n0)
#pragma unroll
        for (int r = 0; r < 16; ++r) {
            int i = (r & 3) + 8 * (r >> 2) + 4 * half;
            vl[i * 72 + n0 * 32 + t] = (_Float16)o_acc[n0][r];
        }

    // ---- write-back: v-rows coalesced h8; a-rows f32 atomicAdd ----
#pragma unroll
    for (int rr = 0; rr < 4; ++rr) {
        int i = rr * 8 + (lane >> 3);
        int c = (lane & 7) * 8;
        h8 val = *(const h8*)&vl[i * 72 + c];
        if (rr < 2) {
            *(h8*)&attnv[(size_t)(bs * 16 + i) * DD + h * HD + c] = val;
        } else {
            float* dst = aaccum + (size_t)(b * 16 + (i - 16)) * DD + h * HD + c;
#pragma unroll
            for (int j = 0; j < 8; ++j)
                atomicAdd(dst + j, (float)val[j]);
        }
    }
}

// ---------------------------------------------------------------------------
// MFMA GEMM 2: out[16512][512] = Av[16512][512] @ Wp + bias, where Av rows
// 0..16383 = attnv (async16 path); tile tm==128 (rows 16384+) staged from
// f32 aaccum with the 1/256 mean folded into the cvt (rows 16448+ read
// aaccum rows 64..127 = zeros; their outputs discarded). 128x128 tiles,
// BK=64 XOR swizzle, grid 129*4=516, tn-fastest, XCD-bijective swizzle.
// Epilogue scatters v-rows -> vp/vf, a-rows -> ap/af.
// ---------------------------------------------------------------------------
__global__ __launch_bounds__(256, 3)
void proj_kernel(const _Float16* __restrict__ A, const float* __restrict__ aaccum,
                 const _Float16* __restrict__ Bt, const float* __restrict__ bp,
                 float* __restrict__ out) {
    __shared__ __align__(16) _Float16 As[128 * 64];   // 16 KB
    __shared__ __align__(16) _Float16 Bs[128 * 64];   // 16 KB
    const int tid = threadIdx.x, lane = tid & 63, wave = tid >> 6;
    const int bid = xcd_swz(blockIdx.x, 129 * 4);
    const int tm = bid >> 2, tn = bid & 3;
    const int m_base = (wave >> 1) * 64, n_base = (wave & 1) * 64;
    const int quad = lane >> 4, l16 = lane & 15;
    const float INV = 1.0f / (float)SS;

    f4 acc[4][4] = {};

    int srow[4], soff[4];
#pragma unroll
    for (int p = 0; p < 4; ++p) {
        int ci = p * 256 + tid;
        int r = ci >> 3, sl = ci & 7;
        srow[p] = r;
        soff[p] = (sl ^ (r & 7)) * 8;
    }

    for (int k0 = 0; k0 < 512; k0 += 64) {
        if (tm < 128) {
#pragma unroll
            for (int p = 0; p < 4; ++p) {
                int ci = p * 256 + tid;
                async16(A + (size_t)(tm * 128 + srow[p]) * 512 + k0 + soff[p],
                        &As[ci * 8]);
            }
        } else {
            // a-row tile: reg-stage from f32 aaccum, fold mean (x 1/256)
#pragma unroll
            for (int p = 0; p < 4; ++p) {
                int ci = p * 256 + tid;
                const float* sp = aaccum + (size_t)srow[p] * 512 + k0 + soff[p];
                float4 w0 = *(const float4*)(sp);
                float4 w1 = *(const float4*)(sp + 4);
                h8 o = { (_Float16)(w0.x * INV), (_Float16)(w0.y * INV),
                         (_Float16)(w0.z * INV), (_Float16)(w0.w * INV),
                         (_Float16)(w1.x * INV), (_Float16)(w1.y * INV),
                         (_Float16)(w1.z * INV), (_Float16)(w1.w * INV) };
                *(h8*)&As[ci * 8] = o;
            }
        }
#pragma unroll
        for (int p = 0; p < 4; ++p) {
            int ci = p * 256 + tid;
            async16(Bt + (size_t)(tn * 128 + srow[p]) * 512 + k0 + soff[p],
                    &Bs[ci * 8]);
        }
        __syncthreads();

#pragma unroll
        for (int kk = 0; kk < 2; ++kk) {
            h8 af[4], bf[4];
#pragma unroll
            for (int mi = 0; mi < 4; ++mi) {
                int m = m_base + mi * 16 + l16;
                int sl = (kk * 4 + quad) ^ (m & 7);
                af[mi] = *(const h8*)&As[m * 64 + sl * 8];
            }
#pragma unroll
            for (int ni = 0; ni < 4; ++ni) {
                int n = n_base + ni * 16 + l16;
                int sl = (kk * 4 + quad) ^ (n & 7);
                bf[ni] = *(const h8*)&Bs[n * 64 + sl * 8];
            }
#pragma unroll
            for (int mi = 0; mi < 4; ++mi)
#pragma unroll
                for (int ni = 0; ni < 4; ++ni)
                    acc[mi][ni] = __builtin_amdgcn_mfma_f32_16x16x32_f16(
                        af[mi], bf[ni], acc[mi][ni], 0, 0, 0);
        }
        __syncthreads();
    }

#pragma unroll
    for (int mi = 0; mi < 4; ++mi)
#pragma unroll
        for (int ni = 0; ni < 4; ++ni) {
            int row0 = tm * 128 + m_base + mi * 16 + quad * 4;
            int col  = tn * 128 + n_base + ni * 16 + l16;
            float bias = bp[col];
#pragma unroll
            for (int r = 0; r < 4; ++r) {
                int row = row0 + r;
                float val = acc[mi][ni][r] + bias;
                if (row < 16384) {
                    int bsq = row >> 4, t = row & 15;
                    int b = bsq >> 8, s = bsq & 255;
                    size_t off = (t < 8)
                        ? (VP_BASE + (size_t)((b * 8 + t) * SS + s) * DD + col)
                        : (VF_BASE + (size_t)((b * 8 + t - 8) * SS + s) * DD + col);
                    out[off] = val;
                } else if (row < 16448) {
                    int idx = row - 16384;
                    int b = idx >> 4, t2 = idx & 15;
                    size_t off = (t2 < 8)
                        ? (AP_BASE + (size_t)(b * 8 + t2) * DD + col)
                        : (AF_BASE + (size_t)(b * 8 + (t2 - 8)) * DD + col);
                    out[off] = val;
                }
            }
        }
}

// ---------------------------------------------------------------------------
extern "C" void kernel_launch(void* const* d_in, const int* in_sizes, int n_in,
                              void* d_out, int out_size, void* d_ws, size_t ws_size,
                              hipStream_t stream) {
    const float* v_p  = (const float*)d_in[0];
    const float* v_f  = (const float*)d_in[1];
    const float* a_p  = (const float*)d_in[2];
    const float* a_f  = (const float*)d_in[3];
    const float* Wqkv = (const float*)d_in[4];
    const float* Wp   = (const float*)d_in[5];
    const float* bp   = (const float*)d_in[6];
    float* out = (float*)d_out;

    // Workspace layout (~87 MB). 4 dispatches (reduce_a eliminated via
    // atomic accumulation into aaccum; zeroed by conv before attn5 runs).
    char* w = (char*)d_ws;
    _Float16* tok   = (_Float16*)w;  w += (size_t)MPAD * DD * 2;    // 16.9 MB
    _Float16* qkv   = (_Float16*)w;  w += (size_t)MPAD * W3 * 2;    // 50.7 MB
    _Float16* attnv = (_Float16*)w;  w += (size_t)MPAD * DD * 2;    // 16.9 MB
    _Float16* Wt    = (_Float16*)w;  w += (size_t)W3 * DD * 2;      //  1.6 MB
    _Float16* Wpt   = (_Float16*)w;  w += (size_t)DD * DD * 2;      //  0.5 MB
    float2*   rope  = (float2*)w;    w += (size_t)1024 * sizeof(float2); // 8 KB
    float*    aaccum= (float*)w;     w += (size_t)128 * DD * sizeof(float); // 256 KB

    conv_kernel<<<8482, 256, 0, stream>>>(v_p, v_f, a_p, a_f, Wqkv, Wp,
                                          tok, Wt, Wpt, rope, aaccum);
    gemm_qkv_kernel<<<129 * 12, 256, 0, stream>>>(tok, Wt, qkv);
    attn5_kernel<<<2048, 256, 0, stream>>>(qkv, rope, attnv, aaccum);
    proj_kernel<<<129 * 4, 256, 0, stream>>>(attnv, aaccum, Wpt, bp, out);
}

// Round 11
// 174.172 us; speedup vs baseline: 2.3383x; 2.3383x over previous
//
#include <hip/hip_runtime.h>
#include <math.h>

// Problem constants (B=4, T_p=T_f=8, S=256, d=512, heads=8)
#define BB   4
#define SS   256
#define DD   512
#define HH   8
#define HD   64
#define HALF 32
#define TT   32      // total tokens per sequence
#define TV   16      // vp+vf tokens (vary per (b,s))
#define W3   1536    // 3*d
#define MROWS  16448 // 16384 v-rows + 64 unique a-rows
#define MPAD   16512 // 129 * 128

#define VP_BASE 0
#define VF_BASE 4194304      // 4*8*256*512
#define AP_BASE 8388608      // 2*4194304
#define AF_BASE 8404992      // AP_BASE + 4*8*512

#define LN10000_OVER_HALF (9.210340371976184f / 32.0f)

typedef _Float16 h2 __attribute__((ext_vector_type(2)));
typedef _Float16 h4 __attribute__((ext_vector_type(4)));
typedef _Float16 h8 __attribute__((ext_vector_type(8)));
typedef float    f4 __attribute__((ext_vector_type(4)));
typedef float    f16v __attribute__((ext_vector_type(16)));

__device__ __forceinline__ float ropefreq(int i) {
    return __expf(-(float)i * LN10000_OVER_HALF);   // 10000^(-i/32)
}

// async global->LDS, 16 bytes per lane (global_load_lds_dwordx4)
typedef __attribute__((address_space(3))) void*       lds_ptr_t;
typedef const __attribute__((address_space(1))) void* gbl_ptr_t;
__device__ __forceinline__ void async16(const void* g, void* l) {
    __builtin_amdgcn_global_load_lds((gbl_ptr_t)g, (lds_ptr_t)l, 16, 0, 0);
}

// Bijective XCD-aware blockIdx swizzle (m204 formula; works for nwg%8 != 0).
// Maps round-robin XCD assignment into contiguous bid chunks per XCD, so
// blocks sharing an A-panel land on the SAME per-XCD L2.
__device__ __forceinline__ int xcd_swz(int bid, int nwg) {
    int q = nwg >> 3, r = nwg & 7;
    int xcd = bid & 7, off = bid >> 3;
    return (xcd < r ? xcd * (q + 1) : r * (q + 1) + (xcd - r) * q) + off;
}

// ---------------------------------------------------------------------------
// Fused prep kernel (R3/R8 anchor form).
// Blocks [0, 8224): gather tokens into fp16 tok[16512][512]
//   rows 0..16383: v-tokens (bs=r/16, t=r%16); rows 16384..16447: a-tokens.
// Blocks [8224, 8480): 64x64 LDS-tile transpose+convert Wqkv->Wt, Wp->Wpt.
// Block 8480: RoPE cos/sin table (t in [0,32), i in [0,32)) -> rope[1024].
// ---------------------------------------------------------------------------
__global__ __launch_bounds__(256)
void conv_kernel(const float* __restrict__ v_p, const float* __restrict__ v_f,
                 const float* __restrict__ a_p, const float* __restrict__ a_f,
                 const float* __restrict__ Wqkv, const float* __restrict__ Wp,
                 _Float16* __restrict__ tok, _Float16* __restrict__ Wt,
                 _Float16* __restrict__ Wpt, float2* __restrict__ rope) {
    __shared__ float tile[64 * 65];
    const int bid = blockIdx.x, tid = threadIdx.x;
    if (bid < 8224) {
        int id = bid * 256 + tid;
        int e  = id * 4;
        int r  = e >> 9, c = e & 511;
        const float* src;
        if (r < 16384) {
            int bs = r >> 4, t = r & 15, b = bs >> 8, s = bs & 255;
            src = (t < 8) ? v_p + (size_t)((b * 8 + t) * SS + s) * DD
                          : v_f + (size_t)((b * 8 + t - 8) * SS + s) * DD;
        } else {
            int idx = r - 16384, b = idx >> 4, t2 = idx & 15;
            src = (t2 < 8) ? a_p + (size_t)(b * 8 + t2) * DD
                           : a_f + (size_t)(b * 8 + (t2 - 8)) * DD;
        }
        float4 v = *(const float4*)(src + c);
        h4 o = { (_Float16)v.x, (_Float16)v.y, (_Float16)v.z, (_Float16)v.w };
        *(h4*)(tok + (size_t)r * DD + c) = o;
    } else if (bid < 8480) {
        int tb = bid - 8224;                 // 0..255
        const float* src; _Float16* dst; int ld, k0, n0;
        if (tb < 192) {                      // Wqkv: 512(k) x 1536(n), 8x24 tiles
            src = Wqkv; dst = Wt; ld = W3;
            k0 = (tb & 7) * 64; n0 = (tb >> 3) * 64;
        } else {                             // Wp: 512 x 512, 8x8 tiles
            int t2 = tb - 192;
            src = Wp; dst = Wpt; ld = DD;
            k0 = (t2 & 7) * 64; n0 = (t2 >> 3) * 64;
        }
#pragma unroll
        for (int p = 0; p < 16; ++p) {
            int idx = p * 256 + tid, rr = idx >> 6, cc = idx & 63;
            tile[rr * 65 + cc] = src[(size_t)(k0 + rr) * ld + n0 + cc];
        }
        __syncthreads();
#pragma unroll
        for (int p = 0; p < 16; ++p) {
            int idx = p * 256 + tid, rr = idx >> 6, cc = idx & 63;
            dst[(size_t)(n0 + rr) * DD + k0 + cc] = (_Float16)tile[cc * 65 + rr];
        }
    } else {
        // RoPE table: rope[t*32 + i] = (cos(t*f_i), sin(t*f_i)), f_i = 10000^(-i/32)
        int idx = tid * 4;
#pragma unroll
        for (int e2 = 0; e2 < 4; ++e2) {
            int ii = (idx + e2) & 31, tt = (idx + e2) >> 5;
            float ang = (float)tt * ropefreq(ii);
            float sn, cs;
            __sincosf(ang, &sn, &cs);
            rope[idx + e2] = make_float2(cs, sn);
        }
    }
}

// ---------------------------------------------------------------------------
// MFMA GEMM 1 (anchor form — dbuf/restage/fused-gather/occ-4 all failed):
// qkv[16512][1536] = tok[16512][512] @ Wqkv (fp16 in/out).
// 128x128 tiles, BK=64, XOR-swizzled LDS (async16 dest linear, frag reads
// 2-way = free). 1-D grid 129*12, tn-fastest; XCD-bijective swizzle so the
// 12 tn-blocks sharing an A-panel hit the same per-XCD L2. 3 blk/CU.
// ---------------------------------------------------------------------------
__global__ __launch_bounds__(256, 3)
void gemm_qkv_kernel(const _Float16* __restrict__ A, const _Float16* __restrict__ Bt,
                     _Float16* __restrict__ C) {
    __shared__ __align__(16) _Float16 As[128 * 64];   // 16 KB
    __shared__ __align__(16) _Float16 Bs[128 * 64];   // 16 KB
    const int tid = threadIdx.x, lane = tid & 63, wave = tid >> 6;
    const int bid = xcd_swz(blockIdx.x, 129 * 12);
    const int tm = bid / 12, tn = bid % 12;
    const int m_base = (wave >> 1) * 64, n_base = (wave & 1) * 64;
    const int quad = lane >> 4, l16 = lane & 15;

    f4 acc[4][4] = {};

    int srow[4], soff[4];
#pragma unroll
    for (int p = 0; p < 4; ++p) {
        int ci = p * 256 + tid;            // [0,1024): r = ci>>3, sl = ci&7
        int r = ci >> 3, sl = ci & 7;
        srow[p] = r;
        soff[p] = (sl ^ (r & 7)) * 8;      // swizzled source k-offset
    }

    for (int k0 = 0; k0 < 512; k0 += 64) {
#pragma unroll
        for (int p = 0; p < 4; ++p) {
            int ci = p * 256 + tid;
            async16(A  + (size_t)(tm * 128 + srow[p]) * 512 + k0 + soff[p],
                    &As[ci * 8]);
            async16(Bt + (size_t)(tn * 128 + srow[p]) * 512 + k0 + soff[p],
                    &Bs[ci * 8]);
        }
        __syncthreads();

#pragma unroll
        for (int kk = 0; kk < 2; ++kk) {
            h8 af[4], bf[4];
#pragma unroll
            for (int mi = 0; mi < 4; ++mi) {
                int m = m_base + mi * 16 + l16;
                int sl = (kk * 4 + quad) ^ (m & 7);
                af[mi] = *(const h8*)&As[m * 64 + sl * 8];
            }
#pragma unroll
            for (int ni = 0; ni < 4; ++ni) {
                int n = n_base + ni * 16 + l16;
                int sl = (kk * 4 + quad) ^ (n & 7);
                bf[ni] = *(const h8*)&Bs[n * 64 + sl * 8];
            }
#pragma unroll
            for (int mi = 0; mi < 4; ++mi)
#pragma unroll
                for (int ni = 0; ni < 4; ++ni)
                    acc[mi][ni] = __builtin_amdgcn_mfma_f32_16x16x32_f16(
                        af[mi], bf[ni], acc[mi][ni], 0, 0, 0);
        }
        __syncthreads();
    }

#pragma unroll
    for (int mi = 0; mi < 4; ++mi)
#pragma unroll
        for (int ni = 0; ni < 4; ++ni) {
            int row = tm * 128 + m_base + mi * 16 + quad * 4;
            int col = tn * 128 + n_base + ni * 16 + l16;
#pragma unroll
            for (int r = 0; r < 4; ++r)
                C[(size_t)(row + r) * W3 + col] = (_Float16)acc[mi][ni][r];
        }
}

// ---------------------------------------------------------------------------
// MFMA attention (R8 anchor): grid 2048 = (b,s) x head-group; 4 waves, wave
// w = head w + 4*hh. Wave-private LDS; no __syncthreads. RoPE from table.
// Softmax via DEFERRED NORMALIZATION: E = exp(S) unnormalized (scores
// bounded ~N(0,1), E <= ~450, fp16-safe); rowsum via ones-B MFMA pair;
// O = (E V) * rcp(rowsum) at the end. a-row outputs go to attna (global
// buffer) + separate reduce_a dispatch — R10 proved atomic accumulation
// serializes at 256-way same-address contention (attn5 30 -> 270 us).
// v-rows -> attnv[bs*16+t][c];  a-rows -> attna[(b*16+t)*256+s][c].
// ---------------------------------------------------------------------------
__global__ __launch_bounds__(256)
void attn5_kernel(const _Float16* __restrict__ qkv, const float2* __restrict__ rope,
                  _Float16* __restrict__ attnv, _Float16* __restrict__ attna) {
    __shared__ _Float16 VlA[4][32 * 72];   // per-wave V tile (reused for O)
    __shared__ _Float16 PlA[4][32 * 40];   // per-wave E tile
    const int bid = blockIdx.x;
    const int bs = bid >> 1, hh = bid & 1, b = bs >> 8, s = bs & 255;
    const int tid = threadIdx.x, wave = tid >> 6, lane = tid & 63;
    const int t = lane & 31, half = lane >> 5;
    _Float16* vl = &VlA[wave][0];
    _Float16* pl = &PlA[wave][0];
    const int h = wave + 4 * hh;

    const size_t row = (t < 16) ? (size_t)(bs * 16 + t)
                                : (size_t)(16384 + b * 16 + (t - 16));
    const _Float16* qp = qkv + row * W3 + h * HD;

    // ---- RoPE coefficients from table (L1/L2-resident, 8 KB) ----
    float ccA[8], ssA[8], ccB[8], ssB[8];
    const float2* rt = rope + t * 32 + 8 * half;
#pragma unroll
    for (int j = 0; j < 8; ++j) {
        float2 eA = rt[j];        // i = 8*half + j
        float2 eB = rt[16 + j];   // i = 16 + 8*half + j
        ccA[j] = eA.x; ssA[j] = eA.y;
        ccB[j] = eB.x; ssB[j] = eB.y;
    }

    // ---- stage V ----
    h8 v0 = *(const h8*)(qp + 2 * DD + 32 * half);
    h8 v1 = *(const h8*)(qp + 2 * DD + 32 * half + 8);
    h8 v2 = *(const h8*)(qp + 2 * DD + 32 * half + 16);
    h8 v3 = *(const h8*)(qp + 2 * DD + 32 * half + 24);
    *(h8*)&vl[t * 72 + 32 * half +  0] = v0;
    *(h8*)&vl[t * 72 + 32 * half +  8] = v1;
    *(h8*)&vl[t * 72 + 32 * half + 16] = v2;
    *(h8*)&vl[t * 72 + 32 * half + 24] = v3;

    // ---- load Q,K chunks + in-register RoPE ----
    h8 q0 = *(const h8*)(qp + 8 * half);
    h8 q1 = *(const h8*)(qp + 8 * half + 16);
    h8 q2 = *(const h8*)(qp + 8 * half + 32);
    h8 q3 = *(const h8*)(qp + 8 * half + 48);
    h8 k0 = *(const h8*)(qp + DD + 8 * half);
    h8 k1 = *(const h8*)(qp + DD + 8 * half + 16);
    h8 k2 = *(const h8*)(qp + DD + 8 * half + 32);
    h8 k3 = *(const h8*)(qp + DD + 8 * half + 48);

    h8 qf0, qf1, qf2, qf3, kf0, kf1, kf2, kf3;
#pragma unroll
    for (int j = 0; j < 8; ++j) {
        float x1 = (float)q0[j], x2 = (float)q2[j];
        qf0[j] = (_Float16)(0.125f * (x1 * ccA[j] - x2 * ssA[j]));
        qf2[j] = (_Float16)(0.125f * (x2 * ccA[j] + x1 * ssA[j]));
        x1 = (float)q1[j]; x2 = (float)q3[j];
        qf1[j] = (_Float16)(0.125f * (x1 * ccB[j] - x2 * ssB[j]));
        qf3[j] = (_Float16)(0.125f * (x2 * ccB[j] + x1 * ssB[j]));
        x1 = (float)k0[j]; x2 = (float)k2[j];
        kf0[j] = (_Float16)(x1 * ccA[j] - x2 * ssA[j]);
        kf2[j] = (_Float16)(x2 * ccA[j] + x1 * ssA[j]);
        x1 = (float)k1[j]; x2 = (float)k3[j];
        kf1[j] = (_Float16)(x1 * ccB[j] - x2 * ssB[j]);
        kf3[j] = (_Float16)(x2 * ccB[j] + x1 * ssB[j]);
    }

    // ---- scores ----
    f16v s4 = {};
    s4 = __builtin_amdgcn_mfma_f32_32x32x16_f16(qf0, kf0, s4, 0, 0, 0);
    s4 = __builtin_amdgcn_mfma_f32_32x32x16_f16(qf1, kf1, s4, 0, 0, 0);
    s4 = __builtin_amdgcn_mfma_f32_32x32x16_f16(qf2, kf2, s4, 0, 0, 0);
    s4 = __builtin_amdgcn_mfma_f32_32x32x16_f16(qf3, kf3, s4, 0, 0, 0);

    // ---- E = exp(S), unnormalized (no max-sub, no shuffle reduction) ----
#pragma unroll
    for (int r = 0; r < 16; ++r) {
        float e = __expf(s4[r]);
        int rr = (r & 3) + 8 * (r >> 2) + 4 * half;
        pl[rr * 40 + t] = (_Float16)e;
    }

    // ---- O' = E V ; rowsum = E * ones (same A-fragments, extra MFMA) ----
    h8 onesv;
#pragma unroll
    for (int j = 0; j < 8; ++j) onesv[j] = (_Float16)1.0f;

    h8 pf[2];
#pragma unroll
    for (int kk = 0; kk < 2; ++kk)
        pf[kk] = *(const h8*)&pl[t * 40 + kk * 16 + half * 8];

    f16v o1 = {};
#pragma unroll
    for (int kk = 0; kk < 2; ++kk)
        o1 = __builtin_amdgcn_mfma_f32_32x32x16_f16(pf[kk], onesv, o1, 0, 0, 0);

    f16v o_acc[2];
#pragma unroll
    for (int n0 = 0; n0 < 2; ++n0) {
        f16v o = {};
#pragma unroll
        for (int kk = 0; kk < 2; ++kk) {
            h8 vf;
#pragma unroll
            for (int jj = 0; jj < 8; ++jj)
                vf[jj] = vl[(kk * 16 + half * 8 + jj) * 72 + n0 * 32 + t];
            o = __builtin_amdgcn_mfma_f32_32x32x16_f16(pf[kk], vf, o, 0, 0, 0);
        }
        o_acc[n0] = o;
    }

    // ---- deferred normalization: O = O' / rowsum ----
#pragma unroll
    for (int r = 0; r < 16; ++r) {
        float inv = __builtin_amdgcn_rcpf(o1[r]);
        o_acc[0][r] *= inv;
        o_acc[1][r] *= inv;
    }

    // ---- V tile dead; stage O into it (wave-synchronous) ----
#pragma unroll
    for (int n0 = 0; n0 < 2; ++n0)
#pragma unroll
        for (int r = 0; r < 16; ++r) {
            int i = (r & 3) + 8 * (r >> 2) + 4 * half;
            vl[i * 72 + n0 * 32 + t] = (_Float16)o_acc[n0][r];
        }

    // ---- coalesced write-back ----
#pragma unroll
    for (int rr = 0; rr < 4; ++rr) {
        int i = rr * 8 + (lane >> 3);
        int c = (lane & 7) * 8;
        h8 val = *(const h8*)&vl[i * 72 + c];
        if (rr < 2)
            *(h8*)&attnv[(size_t)(bs * 16 + i) * DD + h * HD + c] = val;
        else
            *(h8*)&attna[(((size_t)b * 16 + (i - 16)) * SS + s) * DD + h * HD + c] = val;
    }
}

// ---------------------------------------------------------------------------
// reduce_a: 256 blocks = (b,t) x 4 col-quarters. Mean over 256 contiguous
// rows of attna -> fp16 abar rows 16384.. of the proj A matrix.
// (Hierarchical pre-reduction — the correct structure; R10's atomic variant
// serialized at 256-way same-address contention.)
// ---------------------------------------------------------------------------
__global__ __launch_bounds__(256)
void reduce_a_kernel(const _Float16* __restrict__ attna, _Float16* __restrict__ abar) {
    __shared__ float red[16][128];        // 8 KB
    const int bid = blockIdx.x;           // 0..255
    const int r = bid >> 2, cq = bid & 3; // r = b*16+t, cq = col quarter
    const int tid = threadIdx.x;
    const int rg = tid >> 4, ch = tid & 15;

    float acc[8] = {};
    const _Float16* base = attna + ((size_t)r * SS + rg * 16) * DD + cq * 128 + ch * 8;
#pragma unroll 4
    for (int i = 0; i < 16; ++i) {
        h8 v = *(const h8*)(base + (size_t)i * DD);
#pragma unroll
        for (int j = 0; j < 8; ++j) acc[j] += (float)v[j];
    }
#pragma unroll
    for (int j = 0; j < 8; ++j) red[rg][ch * 8 + j] = acc[j];
    __syncthreads();

    if (tid < 64) {
        int c = tid * 2;
        float s0 = 0.f, s1 = 0.f;
#pragma unroll
        for (int g = 0; g < 16; ++g) { s0 += red[g][c]; s1 += red[g][c + 1]; }
        h2 o = { (_Float16)(s0 * (1.0f / SS)), (_Float16)(s1 * (1.0f / SS)) };
        *(h2*)&abar[(size_t)r * DD + cq * 128 + c] = o;
    }
}

// ---------------------------------------------------------------------------
// MFMA GEMM 2 (anchor form): out[16512][512] = Av[16512][512] @ Wp + bias,
// where Av rows 0..16383 = attnv (v-rows), 16384..16447 = abar, rest pad.
// 128x128 tiles, BK=64 XOR swizzle, 1-D grid 129*4=516, tn-fastest,
// XCD-bijective swizzle. Epilogue scatters v-rows -> vp/vf, a-rows ->
// ap/af; pad rows discarded.
// ---------------------------------------------------------------------------
__global__ __launch_bounds__(256, 3)
void proj_kernel(const _Float16* __restrict__ A, const _Float16* __restrict__ Bt,
                 const float* __restrict__ bp, float* __restrict__ out) {
    __shared__ __align__(16) _Float16 As[128 * 64];   // 16 KB
    __shared__ __align__(16) _Float16 Bs[128 * 64];   // 16 KB
    const int tid = threadIdx.x, lane = tid & 63, wave = tid >> 6;
    const int bid = xcd_swz(blockIdx.x, 129 * 4);
    const int tm = bid >> 2, tn = bid & 3;
    const int m_base = (wave >> 1) * 64, n_base = (wave & 1) * 64;
    const int quad = lane >> 4, l16 = lane & 15;

    f4 acc[4][4] = {};

    int srow[4], soff[4];
#pragma unroll
    for (int p = 0; p < 4; ++p) {
        int ci = p * 256 + tid;
        int r = ci >> 3, sl = ci & 7;
        srow[p] = r;
        soff[p] = (sl ^ (r & 7)) * 8;
    }

    for (int k0 = 0; k0 < 512; k0 += 64) {
#pragma unroll
        for (int p = 0; p < 4; ++p) {
            int ci = p * 256 + tid;
            async16(A  + (size_t)(tm * 128 + srow[p]) * 512 + k0 + soff[p],
                    &As[ci * 8]);
            async16(Bt + (size_t)(tn * 128 + srow[p]) * 512 + k0 + soff[p],
                    &Bs[ci * 8]);
        }
        __syncthreads();

#pragma unroll
        for (int kk = 0; kk < 2; ++kk) {
            h8 af[4], bf[4];
#pragma unroll
            for (int mi = 0; mi < 4; ++mi) {
                int m = m_base + mi * 16 + l16;
                int sl = (kk * 4 + quad) ^ (m & 7);
                af[mi] = *(const h8*)&As[m * 64 + sl * 8];
            }
#pragma unroll
            for (int ni = 0; ni < 4; ++ni) {
                int n = n_base + ni * 16 + l16;
                int sl = (kk * 4 + quad) ^ (n & 7);
                bf[ni] = *(const h8*)&Bs[n * 64 + sl * 8];
            }
#pragma unroll
            for (int mi = 0; mi < 4; ++mi)
#pragma unroll
                for (int ni = 0; ni < 4; ++ni)
                    acc[mi][ni] = __builtin_amdgcn_mfma_f32_16x16x32_f16(
                        af[mi], bf[ni], acc[mi][ni], 0, 0, 0);
        }
        __syncthreads();
    }

#pragma unroll
    for (int mi = 0; mi < 4; ++mi)
#pragma unroll
        for (int ni = 0; ni < 4; ++ni) {
            int row0 = tm * 128 + m_base + mi * 16 + quad * 4;
            int col  = tn * 128 + n_base + ni * 16 + l16;
            float bias = bp[col];
#pragma unroll
            for (int r = 0; r < 4; ++r) {
                int row = row0 + r;
                float val = acc[mi][ni][r] + bias;
                if (row < 16384) {
                    int bsq = row >> 4, t = row & 15;
                    int b = bsq >> 8, s = bsq & 255;
                    size_t off = (t < 8)
                        ? (VP_BASE + (size_t)((b * 8 + t) * SS + s) * DD + col)
                        : (VF_BASE + (size_t)((b * 8 + t - 8) * SS + s) * DD + col);
                    out[off] = val;
                } else if (row < 16448) {
                    int idx = row - 16384;
                    int b = idx >> 4, t2 = idx & 15;
                    size_t off = (t2 < 8)
                        ? (AP_BASE + (size_t)(b * 8 + t2) * DD + col)
                        : (AF_BASE + (size_t)(b * 8 + (t2 - 8)) * DD + col);
                    out[off] = val;
                }
            }
        }
}

// ---------------------------------------------------------------------------
extern "C" void kernel_launch(void* const* d_in, const int* in_sizes, int n_in,
                              void* d_out, int out_size, void* d_ws, size_t ws_size,
                              hipStream_t stream) {
    const float* v_p  = (const float*)d_in[0];
    const float* v_f  = (const float*)d_in[1];
    const float* a_p  = (const float*)d_in[2];
    const float* a_f  = (const float*)d_in[3];
    const float* Wqkv = (const float*)d_in[4];
    const float* Wp   = (const float*)d_in[5];
    const float* bp   = (const float*)d_in[6];
    float* out = (float*)d_out;

    // Workspace layout (~86.8 MB). attna ALIASES tok (tok dead after
    // gemm_qkv; attna written by attn5 later on stream).
    char* w = (char*)d_ws;
    _Float16* tok   = (_Float16*)w;  w += (size_t)MPAD * DD * 2;    // 16.9 MB
    _Float16* qkv   = (_Float16*)w;  w += (size_t)MPAD * W3 * 2;    // 50.7 MB
    _Float16* attnv = (_Float16*)w;  w += (size_t)MPAD * DD * 2;    // 16.9 MB (incl. abar rows)
    _Float16* Wt    = (_Float16*)w;  w += (size_t)W3 * DD * 2;      //  1.6 MB
    _Float16* Wpt   = (_Float16*)w;  w += (size_t)DD * DD * 2;      //  0.5 MB
    float2*   rope  = (float2*)w;    w += (size_t)1024 * sizeof(float2); // 8 KB
    _Float16* attna = tok;                                          // alias
    _Float16* abar  = attnv + (size_t)16384 * DD;                   // rows 16384..

    conv_kernel<<<8481, 256, 0, stream>>>(v_p, v_f, a_p, a_f, Wqkv, Wp,
                                          tok, Wt, Wpt, rope);
    gemm_qkv_kernel<<<129 * 12, 256, 0, stream>>>(tok, Wt, qkv);
    attn5_kernel<<<2048, 256, 0, stream>>>(qkv, rope, attnv, attna);
    reduce_a_kernel<<<256, 256, 0, stream>>>(attna, abar);
    proj_kernel<<<129 * 4, 256, 0, stream>>>(attnv, Wpt, bp, out);
}